// Round 9
// baseline (4058.390 us; speedup 1.0000x reference)
//
#include <hip/hip_runtime.h>

#define S_LEN 512
#define BATCH 128
#define NH    128
#define NL    3

#define HXS  392   // hx row stride (shorts)
#define INPS 136   // inp row stride (shorts)

// workspace layout (bytes)
#define XP_OFF   0u
#define WP_OFF   16777216u              // 384 frags * 1KB
#define UP_OFF   (WP_OFF + 393216u)     // 1152 frags * 1KB
#define HX_OFF   (UP_OFF + 1179648u)    // 2par*8grp*3l*16row*24chunk*16B = 294912
#define HX_SZ    294912u

typedef float f32x4 __attribute__((ext_vector_type(4)));
typedef short bf16x8 __attribute__((ext_vector_type(8)));
typedef unsigned u32x4 __attribute__((ext_vector_type(4)));
typedef unsigned long long u64;

__device__ __forceinline__ short f2bf(float f) {
    unsigned u = __builtin_bit_cast(unsigned, f);
    u = (u + 0x7FFFu + ((u >> 16) & 1u)) >> 16;
    return (short)u;
}
__device__ __forceinline__ float bf2f_lo(unsigned u) { return __builtin_bit_cast(float, u << 16); }
__device__ __forceinline__ float bf2f_hi(unsigned u) { return __builtin_bit_cast(float, u & 0xFFFF0000u); }
__device__ __forceinline__ float sigm(float x) { return 1.f / (1.f + __expf(-x)); }
__device__ __forceinline__ float tanh_fast(float x) { return 2.f / (1.f + __expf(-2.f * x)) - 1.f; }

// ---------------- K1: xp = x @ lin_w.T + lin_b  ->  bf16 [S*B][H] ----------------
__global__ __launch_bounds__(128) void xp_kernel(const float* __restrict__ x,
        const float* __restrict__ lin_w, const float* __restrict__ lin_b,
        short* __restrict__ xp) {
    __shared__ float xs[8 * 128];
    const int tid = threadIdx.x;
    const long r0 = (long)blockIdx.x * 8;
    for (int rr = 0; rr < 8; ++rr)
        xs[rr * 128 + tid] = x[(r0 + rr) * 128 + tid];
    __syncthreads();
    float acc[8];
    float bias = lin_b[tid];
    #pragma unroll
    for (int rr = 0; rr < 8; ++rr) acc[rr] = bias;
    const float* wrow = lin_w + (long)tid * 128;
    for (int k = 0; k < 128; ++k) {
        float wv = wrow[k];
        #pragma unroll
        for (int rr = 0; rr < 8; ++rr) acc[rr] += xs[rr * 128 + k] * wv;
    }
    for (int rr = 0; rr < 8; ++rr)
        xp[(r0 + rr) * 128 + tid] = f2bf(acc[rr]);
}

// ---------------- K2: pack W,U per (unit, gate-wave) fragment-linear ----------------
__global__ __launch_bounds__(256) void pack_kernel(const float* __restrict__ W,
        const float* __restrict__ U, short* __restrict__ Wp, short* __restrict__ Up) {
    int id = blockIdx.x * 256 + threadIdx.x;     // 98304 = 1536 frags * 64 lanes
    int lane = id & 63;
    int fid = id >> 6;
    int lr = lane & 15, lk = lane >> 4;
    if (fid < 384) {
        int kt = fid & 3, g = (fid >> 2) & 3, unit = fid >> 4;
        int l = unit >> 3, c = unit & 7;
        int row = g * 128 + c * 16 + lr;
        const float* src = W + ((long)(l * 512 + row)) * 128 + kt * 32 + lk * 8;
        short* dst = Wp + (long)fid * 512 + lane * 8;
        #pragma unroll
        for (int j = 0; j < 8; ++j) dst[j] = f2bf(src[j]);
    } else {
        int f = fid - 384;
        int kt = f % 12, gu = f / 12;
        int g = gu & 3, unit = gu >> 2;
        int l = unit >> 3, c = unit & 7;
        int row = g * 128 + c * 16 + lr;
        const float* src = U + ((long)(l * 512 + row)) * 384 + kt * 32 + lk * 8;
        short* dst = Up + (long)f * 512 + lane * 8;
        #pragma unroll
        for (int j = 0; j < 8; ++j) dst[j] = f2bf(src[j]);
    }
}

// chunk geometry: per (slot,grp,l) block = 16 rows x 24 chunks x 16B.
// chunk m = c*3 + j: holds shorts [6j .. 6j+valid) of publisher c's 16 cols, valid = (j==2)?4:6.
// 16B = [u32 d0][u32 d1][u32 d2][u32 tag], tag = step+1.

// ---------------- main: 192 WGs (24 units x 8 batch groups), tag-chunk sync ----------------
__global__ __launch_bounds__(256, 1) void lstm_kernel(
    const short* __restrict__ xp, const short* __restrict__ Wp,
    const short* __restrict__ Up, const float* __restrict__ Gp,
    char* __restrict__ hexch, float* __restrict__ out)
{
    __shared__ short hx_lds[16 * HXS];        // 12544 B
    __shared__ short inp_lds[16 * INPS];      //  4352 B
    __shared__ float gates_lds[4 * 16 * 17];  //  4352 B
    __shared__ float G_lds[NL * 128];         //  1536 B
    __shared__ short hsl[16 * 16];            //   512 B

    const int tid  = threadIdx.x;
    const int lane = tid & 63;
    const int w    = tid >> 6;        // wave 0..3 = gate index
    const int lr   = lane & 15;
    const int lk   = lane >> 4;
    const int grp  = blockIdx.x & 7;
    const int unit = blockIdx.x >> 3;
    const int l    = unit >> 3;
    const int c    = unit & 7;
    const int b0   = grp * 16;
    const int bb   = tid >> 4;
    const int nn   = tid & 15;

    // ---- weights resident in VGPRs, pinned ----
    bf16x8 ufr[12], wfr[4];
    {
        const short* ub = Up + ((long)(unit * 4 + w) * 12) * 512 + lane * 8;
        #pragma unroll
        for (int kt = 0; kt < 12; ++kt) ufr[kt] = *(const bf16x8*)(ub + kt * 512);
        const short* wb = Wp + ((long)(unit * 4 + w) * 4) * 512 + lane * 8;
        #pragma unroll
        for (int kt = 0; kt < 4; ++kt) wfr[kt] = *(const bf16x8*)(wb + kt * 512);
    }
    #pragma unroll
    for (int kt = 0; kt < 12; ++kt) asm volatile("" : "+v"(ufr[kt]));
    #pragma unroll
    for (int kt = 0; kt < 4; ++kt)  asm volatile("" : "+v"(wfr[kt]));

    for (int i = tid; i < NL * 128; i += 256) G_lds[i] = Gp[i];
    float c_reg = 0.f;
    __syncthreads();

    // per-chunk (off, valid/2) tables for a lane's 6 consecutive chunks (cols sub*32+off)
    const int offs[6] = {0, 6, 12, 16, 22, 28};
    const int nw[6]   = {3, 3, 2, 3, 3, 2};

    for (int t = 0; t < S_LEN; ++t) {
        const int par  = t & 1;
        const int ppar = par ^ 1;

        bf16x8 xa[4];
        if (l == 0) {
            const short* xp_t = xp + ((long)t * BATCH + b0) * 128;
            #pragma unroll
            for (int kt = 0; kt < 4; ++kt)
                xa[kt] = *(const bf16x8*)(xp_t + lr * 128 + kt * 32 + lk * 8);
        }

        // ================= U phase: wave w<3 owns layer w of h(t-1) =================
        if (t == 0) {
            for (int i = tid; i < 16 * HXS; i += 256) hx_lds[i] = 0;
        } else if (w < 3) {
            const int p = lane >> 2, sub = lane & 3;
            const unsigned want = (unsigned)t;   // tag of h(t-1)
            const u64 abase = (u64)(hexch + (size_t)(((ppar * 8 + grp) * 3 + w)) * 6144
                                          + ((size_t)p * 24 + sub * 6) * 16);
            u32x4 q0, q1, q2, q3, q4, q5;
            for (int rounds = 0;; ++rounds) {
                asm volatile(
                    "global_load_dwordx4 %0, %6, off sc0 sc1\n\t"
                    "global_load_dwordx4 %1, %6, off offset:16 sc0 sc1\n\t"
                    "global_load_dwordx4 %2, %6, off offset:32 sc0 sc1\n\t"
                    "global_load_dwordx4 %3, %6, off offset:48 sc0 sc1\n\t"
                    "global_load_dwordx4 %4, %6, off offset:64 sc0 sc1\n\t"
                    "global_load_dwordx4 %5, %6, off offset:80 sc0 sc1\n\t"
                    "s_waitcnt vmcnt(0)"
                    : "=&v"(q0), "=&v"(q1), "=&v"(q2), "=&v"(q3), "=&v"(q4), "=&v"(q5)
                    : "v"(abase) : "memory");
                bool fresh = (q0[3] == want) && (q1[3] == want) && (q2[3] == want)
                          && (q3[3] == want) && (q4[3] == want) && (q5[3] == want);
                if (__all(fresh) || rounds > 262144) break;
            }
            // gh = sigm(h[p,:] . G[w])  (quad-split over 4 lanes)
            const float* gb = &G_lds[w * 128 + sub * 32];
            float s = 0.f;
            u32x4 qs[6] = {q0, q1, q2, q3, q4, q5};
            #pragma unroll
            for (int k = 0; k < 6; ++k)
                #pragma unroll
                for (int i = 0; i < 3; ++i)
                    if (i < nw[k]) {
                        unsigned wd = qs[k][i];
                        s += bf2f_lo(wd) * gb[offs[k] + 2 * i]
                           + bf2f_hi(wd) * gb[offs[k] + 2 * i + 1];
                    }
            s += __shfl_xor(s, 1, 64);
            s += __shfl_xor(s, 2, 64);
            float gh = sigm(s);
            // hx = gh * h  (bf16, into fragment-readable LDS)
            #pragma unroll
            for (int k = 0; k < 6; ++k)
                #pragma unroll
                for (int i = 0; i < 3; ++i)
                    if (i < nw[k]) {
                        unsigned wd = qs[k][i];
                        unsigned r = (unsigned)(unsigned short)f2bf(gh * bf2f_lo(wd))
                                   | ((unsigned)(unsigned short)f2bf(gh * bf2f_hi(wd)) << 16);
                        *(unsigned*)&hx_lds[p * HXS + w * 128 + sub * 32 + offs[k] + 2 * i] = r;
                    }
        }
        __syncthreads();   // hx ready

        // ================= U GEMM (split accumulator chains) =================
        f32x4 acc0 = (f32x4){0.f, 0.f, 0.f, 0.f};
        f32x4 acc1 = (f32x4){0.f, 0.f, 0.f, 0.f};
        #pragma unroll
        for (int kt = 0; kt < 12; ++kt) {
            bf16x8 a = *(const bf16x8*)&hx_lds[lr * HXS + kt * 32 + lk * 8];
            if (kt & 1) acc1 = __builtin_amdgcn_mfma_f32_16x16x32_bf16(a, ufr[kt], acc1, 0, 0, 0);
            else        acc0 = __builtin_amdgcn_mfma_f32_16x16x32_bf16(a, ufr[kt], acc0, 0, 0, 0);
        }

        // ================= W phase =================
        if (l == 0) {
            #pragma unroll
            for (int kt = 0; kt < 4; ++kt) {
                if (kt & 1) acc1 = __builtin_amdgcn_mfma_f32_16x16x32_bf16(xa[kt], wfr[kt], acc1, 0, 0, 0);
                else        acc0 = __builtin_amdgcn_mfma_f32_16x16x32_bf16(xa[kt], wfr[kt], acc0, 0, 0, 0);
            }
        } else {
            // tag-gated read of inp = h(t, l-1): 384 chunks over 256 threads (first 128 take 2)
            const unsigned want = (unsigned)(t + 1);
            const u64 base = (u64)(hexch + (size_t)(((par * 8 + grp) * 3 + (l - 1))) * 6144);
            const int ch0 = tid;
            const u64 a0 = base + (size_t)ch0 * 16;
            const u64 a1 = a0 + 4096;            // chunk ch0 + 256
            u32x4 q0, q1;
            if (tid < 128) {
                for (int rounds = 0;; ++rounds) {
                    asm volatile(
                        "global_load_dwordx4 %0, %2, off sc0 sc1\n\t"
                        "global_load_dwordx4 %1, %3, off sc0 sc1\n\t"
                        "s_waitcnt vmcnt(0)"
                        : "=&v"(q0), "=&v"(q1) : "v"(a0), "v"(a1) : "memory");
                    if (__all((q0[3] == want) && (q1[3] == want)) || rounds > 262144) break;
                }
            } else {
                for (int rounds = 0;; ++rounds) {
                    asm volatile(
                        "global_load_dwordx4 %0, %1, off sc0 sc1\n\t"
                        "s_waitcnt vmcnt(0)"
                        : "=&v"(q0) : "v"(a0) : "memory");
                    if (__all(q0[3] == want) || rounds > 262144) break;
                }
            }
            // deposit chunks into inp_lds
            {
                int row = ch0 / 24, m = ch0 % 24, cc = m / 3, j = m % 3;
                int sbase = row * INPS + cc * 16 + 6 * j;
                *(unsigned*)&inp_lds[sbase] = q0[0];
                *(unsigned*)&inp_lds[sbase + 2] = q0[1];
                if (j < 2) *(unsigned*)&inp_lds[sbase + 4] = q0[2];
                if (tid < 128) {
                    int ch1 = ch0 + 256;
                    int row1 = ch1 / 24, m1 = ch1 % 24, c1 = m1 / 3, j1 = m1 % 3;
                    int sb1 = row1 * INPS + c1 * 16 + 6 * j1;
                    *(unsigned*)&inp_lds[sb1] = q1[0];
                    *(unsigned*)&inp_lds[sb1 + 2] = q1[1];
                    if (j1 < 2) *(unsigned*)&inp_lds[sb1 + 4] = q1[2];
                }
            }
            __syncthreads();
            #pragma unroll
            for (int kt = 0; kt < 4; ++kt) {
                bf16x8 a = *(const bf16x8*)&inp_lds[lr * INPS + kt * 32 + lk * 8];
                if (kt & 1) acc1 = __builtin_amdgcn_mfma_f32_16x16x32_bf16(a, wfr[kt], acc1, 0, 0, 0);
                else        acc0 = __builtin_amdgcn_mfma_f32_16x16x32_bf16(a, wfr[kt], acc0, 0, 0, 0);
            }
        }

        // ================= cell =================
        #pragma unroll
        for (int r = 0; r < 4; ++r)
            gates_lds[w * 272 + (lk * 4 + r) * 17 + lr] = acc0[r] + acc1[r];
        __syncthreads();

        float ig = sigm(gates_lds[0 * 272 + bb * 17 + nn]);
        float fg = sigm(gates_lds[1 * 272 + bb * 17 + nn]);
        float gg = tanh_fast(gates_lds[2 * 272 + bb * 17 + nn]);
        float og = sigm(gates_lds[3 * 272 + bb * 17 + nn]);
        float cn = fg * c_reg + ig * gg;
        c_reg = cn;
        float hy = og * tanh_fast(cn);
        hsl[bb * 16 + nn] = f2bf(hy);
        if (t == S_LEN - 1) {
            long o = ((long)(l * BATCH + b0 + bb)) * NH + c * 16 + nn;
            out[o] = hy;
            out[(long)NL * BATCH * NH + o] = cn;
        }
        __syncthreads();

        // ================= publish: tagged 16B chunks, fire-and-forget =================
        if (tid < 48) {
            int row = tid / 3, j = tid % 3;
            const unsigned* hslw = (const unsigned*)hsl;
            unsigned d0, d1, d2;
            if (j < 2) { d0 = hslw[row * 8 + 3 * j]; d1 = hslw[row * 8 + 3 * j + 1]; d2 = hslw[row * 8 + 3 * j + 2]; }
            else       { d0 = hslw[row * 8 + 6];     d1 = hslw[row * 8 + 7];         d2 = 0; }
            u32x4 dq = (u32x4){d0, d1, d2, (unsigned)(t + 1)};
            u64 pa = (u64)(hexch + (size_t)(((par * 8 + grp) * 3 + l)) * 6144
                                 + ((size_t)row * 24 + c * 3 + j) * 16);
            asm volatile("global_store_dwordx4 %0, %1, off sc0 sc1" :: "v"(pa), "v"(dq) : "memory");
        }
        // no wait, no flag — tag rides with the data
    }
}

extern "C" void kernel_launch(void* const* d_in, const int* in_sizes, int n_in,
                              void* d_out, int out_size, void* d_ws, size_t ws_size,
                              hipStream_t stream) {
    const float* x     = (const float*)d_in[0];
    const float* lin_w = (const float*)d_in[1];
    const float* lin_b = (const float*)d_in[2];
    const float* W     = (const float*)d_in[3];
    const float* U     = (const float*)d_in[4];
    const float* G     = (const float*)d_in[5];
    float* out = (float*)d_out;

    short* xp    = (short*)((char*)d_ws + XP_OFF);
    short* Wp    = (short*)((char*)d_ws + WP_OFF);
    short* Up    = (short*)((char*)d_ws + UP_OFF);
    char*  hexch = (char*)d_ws + HX_OFF;

    hipMemsetAsync(hexch, 0, HX_SZ, stream);   // clear tags every launch (replay-safe)
    hipLaunchKernelGGL(xp_kernel,   dim3(8192), dim3(128), 0, stream, x, lin_w, lin_b, xp);
    hipLaunchKernelGGL(pack_kernel, dim3(384),  dim3(256), 0, stream, W, U, Wp, Up);
    hipLaunchKernelGGL(lstm_kernel, dim3(192),  dim3(256), 0, stream,
                       xp, Wp, Up, G, hexch, out);
}